// Round 1
// baseline (3888.781 us; speedup 1.0000x reference)
//
#include <hip/hip_runtime.h>

#define T_STEPS 64
#define NN 1024     // nodes
#define BB 64       // batch
#define PP 4        // p == q
#define FF 32       // fgnn
#define KG 4        // kgnn + 1

// GEMM tile config: 64x32 tile, 256 threads, each thread 4x2 outputs
#define BM 64
#define BN 32
#define BKK 32

// MODE 0: C = A@B  (plain store)
// MODE 1: step epilogue: C (=SX, 4096x256) += 0.1*acc; rows<1024 also write
//         u_traj[b,t,n,q] = acc and x_traj[b,t+1,n,q] = new value.
template<int MODE>
__global__ __launch_bounds__(256) void gemm_f32(
    const float* __restrict__ A, const float* __restrict__ Bm, float* __restrict__ C,
    int M, int Ncols, int K, int lda, int ldb, int ldc,
    float* __restrict__ x_traj, float* __restrict__ u_traj, int t)
{
    __shared__ float As[BKK][BM + 4];   // transposed A tile, padded
    __shared__ float Bs[BKK][BN];

    const int tid = threadIdx.x;
    const int tx = tid & 15;          // 16 col groups * TN=2
    const int ty = tid >> 4;          // 16 row groups * TM=4
    const int row0 = blockIdx.y * BM;
    const int col0 = blockIdx.x * BN;

    // loaders: 8 float4-columns, 32 rows
    const int lc4 = tid & 7;
    const int lr  = tid >> 3;         // 0..31

    const float* Arow = A + (size_t)(row0 + lr) * lda + lc4 * 4;
    const float* Brow = Bm + (size_t)lr * ldb + col0 + lc4 * 4;

    // register prefetch (first tile)
    float4 a0 = *(const float4*)(Arow);
    float4 a1 = *(const float4*)(Arow + 32 * (size_t)lda);
    float4 b0 = *(const float4*)(Brow);

    float acc[4][2] = {};

    for (int k0 = 0; k0 < K; k0 += BKK) {
        __syncthreads();
        // store A transposed: As[k][m]
        As[lc4*4+0][lr]    = a0.x; As[lc4*4+1][lr]    = a0.y;
        As[lc4*4+2][lr]    = a0.z; As[lc4*4+3][lr]    = a0.w;
        As[lc4*4+0][lr+32] = a1.x; As[lc4*4+1][lr+32] = a1.y;
        As[lc4*4+2][lr+32] = a1.z; As[lc4*4+3][lr+32] = a1.w;
        *(float4*)&Bs[lr][lc4*4] = b0;
        __syncthreads();

        if (k0 + BKK < K) {   // prefetch next tile while computing
            a0 = *(const float4*)(Arow + (k0 + BKK));
            a1 = *(const float4*)(Arow + (k0 + BKK) + 32 * (size_t)lda);
            b0 = *(const float4*)(Brow + (size_t)(k0 + BKK) * ldb);
        }

        #pragma unroll
        for (int kk = 0; kk < BKK; ++kk) {
            float4 av = *(const float4*)&As[kk][ty*4];
            float2 bv = *(const float2*)&Bs[kk][tx*2];
            acc[0][0] = fmaf(av.x, bv.x, acc[0][0]);
            acc[0][1] = fmaf(av.x, bv.y, acc[0][1]);
            acc[1][0] = fmaf(av.y, bv.x, acc[1][0]);
            acc[1][1] = fmaf(av.y, bv.y, acc[1][1]);
            acc[2][0] = fmaf(av.z, bv.x, acc[2][0]);
            acc[2][1] = fmaf(av.z, bv.y, acc[2][1]);
            acc[3][0] = fmaf(av.w, bv.x, acc[3][0]);
            acc[3][1] = fmaf(av.w, bv.y, acc[3][1]);
        }
    }

    if (MODE == 0) {
        #pragma unroll
        for (int i = 0; i < 4; ++i) {
            int row = row0 + ty*4 + i;
            float* cp = C + (size_t)row * ldc + col0 + tx*2;
            cp[0] = acc[i][0];
            cp[1] = acc[i][1];
        }
    } else {
        const bool isU = (row0 < NN);   // BM=64 divides 1024, so uniform per block
        #pragma unroll
        for (int i = 0; i < 4; ++i) {
            int row = row0 + ty*4 + i;
            float* cp = C + (size_t)row * ldc + col0 + tx*2;
            #pragma unroll
            for (int j = 0; j < 2; ++j) {
                float a = acc[i][j];
                float nv = fmaf(0.1f, a, cp[j]);
                cp[j] = nv;
                if (isU) {
                    int col = col0 + tx*2 + j;
                    int b = col >> 2, q = col & 3;
                    u_traj[((size_t)(b*T_STEPS + t) << 12) + (row << 2) + q] = a;
                    x_traj[((size_t)(b*(T_STEPS+1) + t + 1) << 12) + (row << 2) + q] = nv;
                }
            }
        }
    }
}

// Z = tanh(sum_k SX_k @ H1_k); W = Z @ H2.  One thread per (n, b).
__global__ __launch_bounds__(256) void zw_kernel(const float* __restrict__ SX,
    const float* __restrict__ H1, const float* __restrict__ H2, float* __restrict__ W)
{
    __shared__ float h1s[KG*PP*FF];   // 512
    __shared__ float h2s[FF*PP];      // 128
    const int tid = threadIdx.x;
    for (int i = tid; i < KG*PP*FF; i += 256) h1s[i] = H1[i];
    if (tid < FF*PP) h2s[tid] = H2[tid];
    __syncthreads();

    const int g = blockIdx.x * 256 + tid;     // 0..65535
    const int n = g >> 6, b = g & 63;
    const float* sxp = SX + (size_t)n * 256 + b * 4;

    float sx[16];
    #pragma unroll
    for (int k = 0; k < KG; ++k) {
        float4 v = *(const float4*)(sxp + (size_t)k * (NN * BB * PP));
        sx[k*4+0] = v.x; sx[k*4+1] = v.y; sx[k*4+2] = v.z; sx[k*4+3] = v.w;
    }

    float w0 = 0.f, w1 = 0.f, w2 = 0.f, w3 = 0.f;
    #pragma unroll 4
    for (int f = 0; f < FF; ++f) {
        float z = 0.f;
        #pragma unroll
        for (int kp = 0; kp < 16; ++kp) z = fmaf(sx[kp], h1s[kp*FF + f], z);
        z = tanhf(z);
        w0 = fmaf(z, h2s[f*4+0], w0);
        w1 = fmaf(z, h2s[f*4+1], w1);
        w2 = fmaf(z, h2s[f*4+2], w2);
        w3 = fmaf(z, h2s[f*4+3], w3);
    }
    *(float4*)(W + (size_t)n * 256 + b * 4) = make_float4(w0, w1, w2, w3);
}

// SX_0[n][b*4+p] = x0[b][n][p]; x_traj[b,0,n,p] = x0
__global__ __launch_bounds__(256) void init_x0(const float* __restrict__ x0,
    float* __restrict__ SX, float* __restrict__ x_traj)
{
    const int g = blockIdx.x * 256 + threadIdx.x;  // 0..65535 = b*1024+n
    const int b = g >> 10, n = g & 1023;
    float4 v = *(const float4*)(x0 + (size_t)g * 4);
    *(float4*)(SX + (size_t)n * 256 + b * 4) = v;
    *(float4*)(x_traj + ((size_t)(b * (T_STEPS+1)) << 12) + (n << 2)) = v;
}

extern "C" void kernel_launch(void* const* d_in, const int* in_sizes, int n_in,
                              void* d_out, int out_size, void* d_ws, size_t ws_size,
                              hipStream_t stream)
{
    const float* x0 = (const float*)d_in[0];
    const float* S  = (const float*)d_in[1];
    const float* H1 = (const float*)d_in[2];
    const float* H2 = (const float*)d_in[3];

    float* x_traj = (float*)d_out;                                   // (B, T+1, N, p)
    float* u_traj = x_traj + (size_t)BB * (T_STEPS+1) * NN * PP;     // (B, T, N, q)

    // workspace: P = [S; S^2; S^3; S^4] (4096x1024), SX (4x1024x256), W (1024x256)
    float* Pw = (float*)d_ws;
    float* SX = Pw + (size_t)4 * NN * NN;
    float* Wb = SX + (size_t)4 * NN * BB * PP;

    dim3 blk(256);

    // P_0 = S; P_1 = S@S; P_2 = P_1@S; P_3 = P_2@S
    hipMemcpyAsync(Pw, S, sizeof(float) * NN * NN, hipMemcpyDeviceToDevice, stream);
    dim3 gP(NN / BN, NN / BM);
    gemm_f32<0><<<gP, blk, 0, stream>>>(S,            S, Pw + (size_t)NN*NN,   NN, NN, NN, NN, NN, NN, nullptr, nullptr, 0);
    gemm_f32<0><<<gP, blk, 0, stream>>>(Pw + (size_t)NN*NN,   S, Pw + (size_t)2*NN*NN, NN, NN, NN, NN, NN, NN, nullptr, nullptr, 0);
    gemm_f32<0><<<gP, blk, 0, stream>>>(Pw + (size_t)2*NN*NN, S, Pw + (size_t)3*NN*NN, NN, NN, NN, NN, NN, NN, nullptr, nullptr, 0);

    // SX_0 = x0 (transposed layout), x_traj[:,0] = x0
    init_x0<<<dim3(BB * NN / 256), blk, 0, stream>>>(x0, SX, x_traj);

    // SX_{1..3} = [S;S^2;S^3] @ SX_0
    dim3 gI(BB * PP / BN, 3 * NN / BM);
    gemm_f32<0><<<gI, blk, 0, stream>>>(Pw, SX, SX + (size_t)NN*BB*PP,
                                        3 * NN, BB * PP, NN, NN, BB * PP, BB * PP,
                                        nullptr, nullptr, 0);

    // main rollout: per step one tiny ZW kernel + one stacked GEMM
    dim3 gS(BB * PP / BN, 4 * NN / BM);    // (8, 64)
    for (int t = 0; t < T_STEPS; ++t) {
        zw_kernel<<<dim3(BB * NN / 256), blk, 0, stream>>>(SX, H1, H2, Wb);
        gemm_f32<1><<<gS, blk, 0, stream>>>(Pw, Wb, SX,
                                            4 * NN, BB * PP, NN, NN, BB * PP, BB * PP,
                                            x_traj, u_traj, t);
    }
}

// Round 2
// 1641.821 us; speedup vs baseline: 2.3686x; 2.3686x over previous
//
#include <hip/hip_runtime.h>

#define T_STEPS 64
#define NN 1024
#define BB 64
#define KTOT 1024
#define BKC 128
#define NCHUNK (KTOT / BKC)

typedef __bf16 bf16x8 __attribute__((ext_vector_type(8)));
typedef float f32x4 __attribute__((ext_vector_type(4)));

// ---------------------------------------------------------------------------
// Unified split-bf16 MFMA GEMM core. C = A @ B, K=1024, 64x64 tile, 256 thr.
// A: row-major split planes [rows][1024]; B: transposed split planes [cols][1024].
// 3-term: AhBh + AhBl + AlBh, f32 accumulate.
// MODE 0: write C as split planes (row-major, ld=1024)     [power chain]
// MODE 1: write C as f32 (ld=256)                          [init SX_1..3]
// MODE 2: step: SX += 0.1*C; emit x_traj/u_traj; compute next W^T planes
// ---------------------------------------------------------------------------
template<int MODE>
__global__ __launch_bounds__(256) void gemm_core(
    const __bf16* __restrict__ Ah, const __bf16* __restrict__ Al,
    const __bf16* __restrict__ Bh, const __bf16* __restrict__ Bl,
    __bf16* __restrict__ Oh, __bf16* __restrict__ Ol,
    float* __restrict__ SX,
    float* __restrict__ x_traj, float* __restrict__ u_traj,
    const float* __restrict__ H1, const float* __restrict__ H2,
    __bf16* __restrict__ WToh, __bf16* __restrict__ WTol,
    int t)
{
    int nb, cb;
    if (MODE == 2) {
        // XCD-aware swizzle: xcd = blockIdx%8 gets nb in [8x,8x+8), all 4 cb.
        int l = blockIdx.x;
        int xcd = l & 7, j = l >> 3;
        nb = xcd * 8 + (j & 7);
        cb = j >> 3;
    } else {
        cb = blockIdx.x; nb = blockIdx.y;
    }
    const int c0 = cb * 64;

    __shared__ char sA[2][16384];   // [hi/lo][64 rows][128 bf16], XOR-swizzled
    __shared__ char sB[2][16384];
    __shared__ float ctile[64 * 68];
    __shared__ float h1s[512];
    __shared__ float h2s[128];

    const int tid = threadIdx.x;
    if constexpr (MODE == 2) {
        for (int i = tid; i < 512; i += 256) h1s[i] = H1[i];
        if (tid < 128) h2s[tid] = H2[tid];
    }

    const int lane = tid & 63;
    const int wid  = tid >> 6;
    const int wr = wid >> 1, wc = wid & 1;   // wave tile 32x32 within 64x64

    f32x4 acc[2][2];
    #pragma unroll
    for (int a = 0; a < 2; ++a)
        #pragma unroll
        for (int b = 0; b < 2; ++b)
            acc[a][b] = (f32x4){0.f, 0.f, 0.f, 0.f};

    for (int ch = 0; ch < NCHUNK; ++ch) {
        const int k0 = ch * BKC;
        __syncthreads();
        // ---- stage A/B chunk (reg-staged, swizzled ds_write_b128) ----
        #pragma unroll
        for (int j = 0; j < 4; ++j) {
            const int i = j * 256 + tid;
            const int r = i >> 4, s = i & 15;
            const int d = (r << 8) + ((s << 4) ^ ((r & 15) << 4));
            int gA;
            if (MODE == 2) gA = (r >> 4) * NN + nb * 16 + (r & 15);  // stacked k-blocks
            else           gA = nb * 64 + r;
            {
                const size_t off = (size_t)gA * 1024 + k0 + s * 8;
                uint4 vh = *(const uint4*)(Ah + off);
                uint4 vl = *(const uint4*)(Al + off);
                *(uint4*)(sA[0] + d) = vh;
                *(uint4*)(sA[1] + d) = vl;
            }
            {
                const size_t off = (size_t)(c0 + r) * 1024 + k0 + s * 8;
                uint4 vh = *(const uint4*)(Bh + off);
                uint4 vl = *(const uint4*)(Bl + off);
                *(uint4*)(sB[0] + d) = vh;
                *(uint4*)(sB[1] + d) = vl;
            }
        }
        __syncthreads();
        // ---- MFMA: 4 k-steps of 32 ----
        #pragma unroll
        for (int ks = 0; ks < 4; ++ks) {
            const int kb = ks * 64 + ((lane >> 4) << 4);
            bf16x8 afr[2][2], bfr[2][2];
            #pragma unroll
            for (int rt = 0; rt < 2; ++rt) {
                const int row = wr * 32 + rt * 16 + (lane & 15);
                const int d = (row << 8) + (kb ^ ((row & 15) << 4));
                afr[rt][0] = *(const bf16x8*)(sA[0] + d);
                afr[rt][1] = *(const bf16x8*)(sA[1] + d);
            }
            #pragma unroll
            for (int ct = 0; ct < 2; ++ct) {
                const int row = wc * 32 + ct * 16 + (lane & 15);
                const int d = (row << 8) + (kb ^ ((row & 15) << 4));
                bfr[ct][0] = *(const bf16x8*)(sB[0] + d);
                bfr[ct][1] = *(const bf16x8*)(sB[1] + d);
            }
            #pragma unroll
            for (int rt = 0; rt < 2; ++rt)
                #pragma unroll
                for (int ct = 0; ct < 2; ++ct) {
                    acc[rt][ct] = __builtin_amdgcn_mfma_f32_16x16x32_bf16(afr[rt][0], bfr[ct][0], acc[rt][ct], 0, 0, 0);
                    acc[rt][ct] = __builtin_amdgcn_mfma_f32_16x16x32_bf16(afr[rt][0], bfr[ct][1], acc[rt][ct], 0, 0, 0);
                    acc[rt][ct] = __builtin_amdgcn_mfma_f32_16x16x32_bf16(afr[rt][1], bfr[ct][0], acc[rt][ct], 0, 0, 0);
                }
        }
    }

    if constexpr (MODE == 0 || MODE == 1) {
        #pragma unroll
        for (int rt = 0; rt < 2; ++rt)
            #pragma unroll
            for (int ct = 0; ct < 2; ++ct)
                #pragma unroll
                for (int r = 0; r < 4; ++r) {
                    const int row = wr * 32 + rt * 16 + ((lane >> 4) << 2) + r;
                    const int col = wc * 32 + ct * 16 + (lane & 15);
                    const float v = acc[rt][ct][r];
                    if (MODE == 0) {
                        const size_t o = (size_t)(nb * 64 + row) * 1024 + c0 + col;
                        const __bf16 h = (__bf16)v;
                        Oh[o] = h;
                        Ol[o] = (__bf16)(v - (float)h);
                    } else {
                        SX[(size_t)(nb * 64 + row) * 256 + c0 + col] = v;
                    }
                }
    }

    if constexpr (MODE == 2) {
        #pragma unroll
        for (int rt = 0; rt < 2; ++rt)
            #pragma unroll
            for (int ct = 0; ct < 2; ++ct)
                #pragma unroll
                for (int r = 0; r < 4; ++r) {
                    const int row = wr * 32 + rt * 16 + ((lane >> 4) << 2) + r;
                    const int col = wc * 32 + ct * 16 + (lane & 15);
                    ctile[row * 68 + col] = acc[rt][ct][r];
                }
        __syncthreads();

        const int i  = tid & 15;       // n_local
        const int bl = tid >> 4;       // b_local
        const int n  = nb * 16 + i;
        const int bg = cb * 16 + bl;
        const int colb = bl * 4;

        float nv[4][4];
        #pragma unroll
        for (int k = 0; k < 4; ++k) {
            f32x4 inc;
            #pragma unroll
            for (int p = 0; p < 4; ++p) inc[p] = ctile[(k * 16 + i) * 68 + colb + p];
            const size_t so = (size_t)(k * NN + n) * 256 + c0 + colb;
            f32x4 old = *(const f32x4*)(SX + so);
            f32x4 nw;
            #pragma unroll
            for (int p = 0; p < 4; ++p) nw[p] = old[p] + 0.1f * inc[p];
            *(f32x4*)(SX + so) = nw;
            #pragma unroll
            for (int p = 0; p < 4; ++p) nv[k][p] = nw[p];
            if (k == 0) {
                const size_t xo = (size_t)bg * ((T_STEPS + 1) * 4096) + (size_t)(t + 1) * 4096 + n * 4;
                *(f32x4*)(x_traj + xo) = nw;
                const size_t uo = (size_t)bg * (T_STEPS * 4096) + (size_t)t * 4096 + n * 4;
                *(f32x4*)(u_traj + uo) = inc;
            }
        }
        float w4[4] = {0.f, 0.f, 0.f, 0.f};
        #pragma unroll 4
        for (int f = 0; f < 32; ++f) {
            float z = 0.f;
            #pragma unroll
            for (int k = 0; k < 4; ++k)
                #pragma unroll
                for (int p = 0; p < 4; ++p)
                    z = fmaf(nv[k][p], h1s[(k * 4 + p) * 32 + f], z);
            z = tanhf(z);
            #pragma unroll
            for (int q = 0; q < 4; ++q) w4[q] = fmaf(z, h2s[f * 4 + q], w4[q]);
        }
        #pragma unroll
        for (int q = 0; q < 4; ++q) {
            const size_t o = (size_t)(c0 + colb + q) * 1024 + n;
            const __bf16 h = (__bf16)w4[q];
            WToh[o] = h;
            WTol[o] = (__bf16)(w4[q] - (float)h);
        }
    }
}

// S -> split planes (row-major into Astack rows [0,1024)) and transposed split planes ST
__global__ __launch_bounds__(1024) void split_S(const float* __restrict__ S,
    __bf16* __restrict__ Ah, __bf16* __restrict__ Al,
    __bf16* __restrict__ STh, __bf16* __restrict__ STl)
{
    __shared__ float tile[32][33];
    const int tx = threadIdx.x & 31, ty = threadIdx.x >> 5;
    const int r0 = blockIdx.y * 32, c0 = blockIdx.x * 32;
    const float v = S[(size_t)(r0 + ty) * 1024 + c0 + tx];
    tile[ty][tx] = v;
    {
        const __bf16 h = (__bf16)v;
        const size_t o = (size_t)(r0 + ty) * 1024 + c0 + tx;
        Ah[o] = h; Al[o] = (__bf16)(v - (float)h);
    }
    __syncthreads();
    const float w = tile[tx][ty];
    const __bf16 h = (__bf16)w;
    const size_t o = (size_t)(c0 + ty) * 1024 + r0 + tx;
    STh[o] = h; STl[o] = (__bf16)(w - (float)h);
}

// SX_0 = x0^T layout; x_traj[:,0]; x0 transposed split planes for init GEMM B
__global__ __launch_bounds__(256) void init_x0(const float* __restrict__ x0,
    float* __restrict__ SX, float* __restrict__ x_traj,
    __bf16* __restrict__ X0Th, __bf16* __restrict__ X0Tl)
{
    const int g = blockIdx.x * 256 + threadIdx.x;   // b*1024+n
    const int b = g >> 10, n = g & 1023;
    const f32x4 v = *(const f32x4*)(x0 + (size_t)g * 4);
    *(f32x4*)(SX + (size_t)n * 256 + b * 4) = v;
    *(f32x4*)(x_traj + (size_t)b * ((T_STEPS + 1) * 4096) + n * 4) = v;
    #pragma unroll
    for (int p = 0; p < 4; ++p) {
        const __bf16 h = (__bf16)v[p];
        const size_t o = (size_t)(b * 4 + p) * 1024 + n;
        X0Th[o] = h; X0Tl[o] = (__bf16)(v[p] - (float)h);
    }
}

// W_0 from SX (f32) -> W^T split planes
__global__ __launch_bounds__(256) void w0_kernel(const float* __restrict__ SX,
    const float* __restrict__ H1, const float* __restrict__ H2,
    __bf16* __restrict__ WTh, __bf16* __restrict__ WTl)
{
    __shared__ float h1s[512], h2s[128];
    const int tid = threadIdx.x;
    for (int i = tid; i < 512; i += 256) h1s[i] = H1[i];
    if (tid < 128) h2s[tid] = H2[tid];
    __syncthreads();
    const int g = blockIdx.x * 256 + tid;     // b*1024+n
    const int b = g >> 10, n = g & 1023;
    float sx[16];
    #pragma unroll
    for (int k = 0; k < 4; ++k) {
        const f32x4 v = *(const f32x4*)(SX + (size_t)(k * NN + n) * 256 + b * 4);
        #pragma unroll
        for (int p = 0; p < 4; ++p) sx[k * 4 + p] = v[p];
    }
    float w4[4] = {0.f, 0.f, 0.f, 0.f};
    #pragma unroll 4
    for (int f = 0; f < 32; ++f) {
        float z = 0.f;
        #pragma unroll
        for (int kp = 0; kp < 16; ++kp) z = fmaf(sx[kp], h1s[kp * 32 + f], z);
        z = tanhf(z);
        #pragma unroll
        for (int q = 0; q < 4; ++q) w4[q] = fmaf(z, h2s[f * 4 + q], w4[q]);
    }
    #pragma unroll
    for (int q = 0; q < 4; ++q) {
        const size_t o = (size_t)(b * 4 + q) * 1024 + n;
        const __bf16 h = (__bf16)w4[q];
        WTh[o] = h; WTl[o] = (__bf16)(w4[q] - (float)h);
    }
}

extern "C" void kernel_launch(void* const* d_in, const int* in_sizes, int n_in,
                              void* d_out, int out_size, void* d_ws, size_t ws_size,
                              hipStream_t stream)
{
    const float* x0 = (const float*)d_in[0];
    const float* S  = (const float*)d_in[1];
    const float* H1 = (const float*)d_in[2];
    const float* H2 = (const float*)d_in[3];

    float* x_traj = (float*)d_out;
    float* u_traj = x_traj + (size_t)BB * (T_STEPS + 1) * NN * 4;

    // workspace carve
    __bf16* Ah = (__bf16*)d_ws;                      // [4096][1024]
    __bf16* Al = Ah + (size_t)4096 * 1024;
    float*  SX = (float*)(Al + (size_t)4096 * 1024); // [4096][256] f32
    __bf16* STh = (__bf16*)SX;                       // aliases SX (setup only)
    __bf16* STl = STh + (size_t)1024 * 1024;
    __bf16* WT0h = (__bf16*)(SX + (size_t)4096 * 256);
    __bf16* WT0l = WT0h + 256 * 1024;
    __bf16* WT1h = WT0l + 256 * 1024;
    __bf16* WT1l = WT1h + 256 * 1024;
    __bf16* X0Th = WT1h;                             // aliases WT1 (setup only)
    __bf16* X0Tl = WT1l;

    // 1) split S into Astack rows [0,1024) and transposed planes ST
    split_S<<<dim3(32, 32), 1024, 0, stream>>>(S, Ah, Al, STh, STl);

    // 2) power chain: S^{j+1} = S^j @ S  (B = ST planes), rows j*1024..
    for (int j = 1; j <= 3; ++j) {
        gemm_core<0><<<dim3(16, 16), 256, 0, stream>>>(
            Ah + (size_t)(j - 1) * 1024 * 1024, Al + (size_t)(j - 1) * 1024 * 1024,
            STh, STl,
            Ah + (size_t)j * 1024 * 1024, Al + (size_t)j * 1024 * 1024,
            nullptr, nullptr, nullptr, nullptr, nullptr, nullptr, nullptr, 0);
    }

    // 3) SX_0 = x0 (NOTE: clobbers ST region -> must run after power chain)
    init_x0<<<dim3(256), 256, 0, stream>>>(x0, SX, x_traj, X0Th, X0Tl);

    // 4) SX_{1..3} = [S;S^2;S^3] @ x0
    gemm_core<1><<<dim3(4, 48), 256, 0, stream>>>(
        Ah, Al, X0Th, X0Tl, nullptr, nullptr,
        SX + (size_t)1024 * 256, nullptr, nullptr, nullptr, nullptr,
        nullptr, nullptr, 0);

    // 5) W_0
    w0_kernel<<<dim3(256), 256, 0, stream>>>(SX, H1, H2, WT0h, WT0l);

    // 6) rollout: one fused kernel per step, W double-buffered
    for (int t = 0; t < T_STEPS; ++t) {
        const __bf16* bh = (t & 1) ? WT1h : WT0h;
        const __bf16* bl = (t & 1) ? WT1l : WT0l;
        __bf16* oh = (t & 1) ? WT0h : WT1h;
        __bf16* ol = (t & 1) ? WT0l : WT1l;
        gemm_core<2><<<dim3(256), 256, 0, stream>>>(
            Ah, Al, bh, bl, nullptr, nullptr,
            SX, x_traj, u_traj, H1, H2, oh, ol, t);
    }
}

// Round 3
// 1567.557 us; speedup vs baseline: 2.4808x; 1.0474x over previous
//
#include <hip/hip_runtime.h>

#define T_STEPS 64
#define NN 1024
#define BB 64
#define KTOT 1024
#define BKC 128
#define NCHUNK (KTOT / BKC)

#define DEPTH 5
#define NSLOT 8

typedef __bf16 bf16x8 __attribute__((ext_vector_type(8)));
typedef float f32x4 __attribute__((ext_vector_type(4)));

__device__ inline void gload16(const void* g, void* l) {
    __builtin_amdgcn_global_load_lds(
        (const __attribute__((address_space(1))) void*)g,
        (__attribute__((address_space(3))) void*)l, 16, 0, 0);
}

// ===========================================================================
// Fused rollout step. A/B operands pre-swizzled into MFMA fragment order:
//   frag[blk16][kblk32][lane64][8elems], lane = (idx&15) + 16*((k>>3)&3)
// global_load_lds writes LDS linearly == fragment-ready; ds_read stride-1.
// 8-slot LDS ring, counted vmcnt (T4), raw s_barrier per kblk (m201 pattern).
// ===========================================================================
__global__ __launch_bounds__(256) void step_kernel(
    const __bf16* __restrict__ AhF, const __bf16* __restrict__ AlF,
    const __bf16* __restrict__ BhF, const __bf16* __restrict__ BlF,
    float* __restrict__ SX, float* __restrict__ x_traj, float* __restrict__ u_traj,
    const float* __restrict__ H1, const float* __restrict__ H2,
    __bf16* __restrict__ WOh, __bf16* __restrict__ WOl, int t)
{
    __shared__ char ring[NSLOT][16384];    // 16 segs x 1KB per slot
    __shared__ float h1s[512];
    __shared__ float h2s[128];

    const int tid = threadIdx.x;
    const int lane = tid & 63;
    const int wid = tid >> 6;
    const int wr = wid >> 1, wc = wid & 1;

    for (int i = tid; i < 512; i += 256) h1s[i] = H1[i];
    if (tid < 128) h2s[tid] = H2[tid];

    // XCD-aware: xcd gets contiguous nb range (2MB A-slice L2-resident)
    const int l = blockIdx.x;
    const int xcd = l & 7, jj = l >> 3;
    const int nb = xcd * 8 + (jj & 7);
    const int cb = jj >> 3;

    // wave's 4 gload segments: s = wid*4 + js
    const __bf16* gsrc[4];
    int segoff[4];
    #pragma unroll
    for (int js = 0; js < 4; ++js) {
        const int s = wid * 4 + js;
        const __bf16* base;
        int blk;
        if (s < 8) { const int p = s >> 1; blk = p * 64 + nb; base = (s & 1) ? AlF : AhF; }
        else       { const int c = (s - 8) >> 1; blk = cb * 4 + c; base = (s & 1) ? BlF : BhF; }
        gsrc[js] = base + ((size_t)blk * 32) * 512 + (size_t)lane * 8;
        segoff[js] = s * 1024;   // bytes within slot
    }

    f32x4 acc[2][2];
    #pragma unroll
    for (int a = 0; a < 2; ++a)
        #pragma unroll
        for (int b = 0; b < 2; ++b)
            acc[a][b] = (f32x4){0.f, 0.f, 0.f, 0.f};

    // prologue: issue chunks 0..DEPTH-1
    #pragma unroll
    for (int k = 0; k < DEPTH; ++k) {
        char* slot = ring[k & (NSLOT - 1)];
        #pragma unroll
        for (int js = 0; js < 4; ++js)
            gload16(gsrc[js] + (size_t)k * 512, slot + segoff[js]);
    }

    #pragma unroll
    for (int k = 0; k < 32; ++k) {
        // counted wait: own chunk-k segments landed (tail shrinks)
        if (k <= 27)      asm volatile("s_waitcnt vmcnt(16)" ::: "memory");
        else if (k == 28) asm volatile("s_waitcnt vmcnt(12)" ::: "memory");
        else if (k == 29) asm volatile("s_waitcnt vmcnt(8)" ::: "memory");
        else if (k == 30) asm volatile("s_waitcnt vmcnt(4)" ::: "memory");
        else              asm volatile("s_waitcnt vmcnt(0)" ::: "memory");
        __builtin_amdgcn_sched_barrier(0);
        __builtin_amdgcn_s_barrier();   // all waves waited -> chunk k complete

        const char* sb = ring[k & (NSLOT - 1)];
        bf16x8 ah[2], al[2], bh[2], bl[2];
        #pragma unroll
        for (int rt = 0; rt < 2; ++rt) {
            const int r = wr * 2 + rt;
            ah[rt] = *(const bf16x8*)(sb + (r * 2 + 0) * 1024 + lane * 16);
            al[rt] = *(const bf16x8*)(sb + (r * 2 + 1) * 1024 + lane * 16);
        }
        #pragma unroll
        for (int ct = 0; ct < 2; ++ct) {
            const int c = wc * 2 + ct;
            bh[ct] = *(const bf16x8*)(sb + 8192 + (c * 2 + 0) * 1024 + lane * 16);
            bl[ct] = *(const bf16x8*)(sb + 8192 + (c * 2 + 1) * 1024 + lane * 16);
        }

        // prefetch chunk k+DEPTH (slot (k+DEPTH)&7, consumed 3 barriers ago)
        if (k + DEPTH < 32) {
            char* slot = ring[(k + DEPTH) & (NSLOT - 1)];
            #pragma unroll
            for (int js = 0; js < 4; ++js)
                gload16(gsrc[js] + (size_t)(k + DEPTH) * 512, slot + segoff[js]);
        }

        #pragma unroll
        for (int rt = 0; rt < 2; ++rt)
            #pragma unroll
            for (int ct = 0; ct < 2; ++ct) {
                acc[rt][ct] = __builtin_amdgcn_mfma_f32_16x16x32_bf16(ah[rt], bh[ct], acc[rt][ct], 0, 0, 0);
                acc[rt][ct] = __builtin_amdgcn_mfma_f32_16x16x32_bf16(ah[rt], bl[ct], acc[rt][ct], 0, 0, 0);
                acc[rt][ct] = __builtin_amdgcn_mfma_f32_16x16x32_bf16(al[rt], bh[ct], acc[rt][ct], 0, 0, 0);
            }
    }

    // ---- epilogue: ctile aliases ring slots 0-1 (safe: all reads done) ----
    float* ctile = (float*)ring;
    #pragma unroll
    for (int rt = 0; rt < 2; ++rt)
        #pragma unroll
        for (int ct = 0; ct < 2; ++ct)
            #pragma unroll
            for (int r = 0; r < 4; ++r) {
                const int row = wr * 32 + rt * 16 + ((lane >> 4) << 2) + r;
                const int col = wc * 32 + ct * 16 + (lane & 15);
                ctile[row * 68 + col] = acc[rt][ct][r];
            }
    __syncthreads();

    const int i  = tid & 15;       // node-local
    const int blc = tid >> 4;      // batch-local
    const int n  = nb * 16 + i;
    const int bg = cb * 16 + blc;
    const int colb = blc * 4;

    float nv[4][4];
    #pragma unroll
    for (int k = 0; k < 4; ++k) {
        f32x4 inc;
        #pragma unroll
        for (int p = 0; p < 4; ++p) inc[p] = ctile[(k * 16 + i) * 68 + colb + p];
        const size_t so = (size_t)(k * NN + n) * 256 + cb * 64 + colb;
        f32x4 old = *(const f32x4*)(SX + so);
        f32x4 nw;
        #pragma unroll
        for (int p = 0; p < 4; ++p) nw[p] = old[p] + 0.1f * inc[p];
        *(f32x4*)(SX + so) = nw;
        #pragma unroll
        for (int p = 0; p < 4; ++p) nv[k][p] = nw[p];
        if (k == 0) {
            const size_t xo = (size_t)bg * ((T_STEPS + 1) * 4096) + (size_t)(t + 1) * 4096 + n * 4;
            *(f32x4*)(x_traj + xo) = nw;
            const size_t uo = (size_t)bg * (T_STEPS * 4096) + (size_t)t * 4096 + n * 4;
            *(f32x4*)(u_traj + uo) = inc;
        }
    }
    float w4[4] = {0.f, 0.f, 0.f, 0.f};
    #pragma unroll 4
    for (int f = 0; f < 32; ++f) {
        float z = 0.f;
        #pragma unroll
        for (int k = 0; k < 4; ++k)
            #pragma unroll
            for (int p = 0; p < 4; ++p)
                z = fmaf(nv[k][p], h1s[(k * 4 + p) * 32 + f], z);
        z = tanhf(z);
        #pragma unroll
        for (int q = 0; q < 4; ++q) w4[q] = fmaf(z, h2s[f * 4 + q], w4[q]);
    }
    // W -> fragment layout: col=(cb*16+blc)*4+q, k-index = n
    const int kblkw = n >> 5;
    const int lhi = ((n >> 3) & 3) << 4;
    const int jw = n & 7;
    #pragma unroll
    for (int q = 0; q < 4; ++q) {
        const int col = bg * 4 + q;
        const int colblk = col >> 4;
        const int lanew = (col & 15) + lhi;
        const size_t o = (((size_t)colblk * 32 + kblkw) * 64 + lanew) * 8 + jw;
        const __bf16 h = (__bf16)w4[q];
        WOh[o] = h;
        WOl[o] = (__bf16)(w4[q] - (float)h);
    }
}

// ===========================================================================
// Setup-phase kernels (R2-proven, LDS-staged split-bf16 GEMM, MODE 0/1)
// ===========================================================================
template<int MODE>
__global__ __launch_bounds__(256) void gemm_core(
    const __bf16* __restrict__ Ah, const __bf16* __restrict__ Al,
    const __bf16* __restrict__ Bh, const __bf16* __restrict__ Bl,
    __bf16* __restrict__ Oh, __bf16* __restrict__ Ol,
    float* __restrict__ SX)
{
    const int cb = blockIdx.x, nb = blockIdx.y;
    const int c0 = cb * 64;

    __shared__ char sA[2][16384];
    __shared__ char sB[2][16384];

    const int tid = threadIdx.x;
    const int lane = tid & 63;
    const int wid  = tid >> 6;
    const int wr = wid >> 1, wc = wid & 1;

    f32x4 acc[2][2];
    #pragma unroll
    for (int a = 0; a < 2; ++a)
        #pragma unroll
        for (int b = 0; b < 2; ++b)
            acc[a][b] = (f32x4){0.f, 0.f, 0.f, 0.f};

    for (int ch = 0; ch < NCHUNK; ++ch) {
        const int k0 = ch * BKC;
        __syncthreads();
        #pragma unroll
        for (int j = 0; j < 4; ++j) {
            const int i = j * 256 + tid;
            const int r = i >> 4, s = i & 15;
            const int d = (r << 8) + ((s << 4) ^ ((r & 15) << 4));
            const int gA = nb * 64 + r;
            {
                const size_t off = (size_t)gA * 1024 + k0 + s * 8;
                *(uint4*)(sA[0] + d) = *(const uint4*)(Ah + off);
                *(uint4*)(sA[1] + d) = *(const uint4*)(Al + off);
            }
            {
                const size_t off = (size_t)(c0 + r) * 1024 + k0 + s * 8;
                *(uint4*)(sB[0] + d) = *(const uint4*)(Bh + off);
                *(uint4*)(sB[1] + d) = *(const uint4*)(Bl + off);
            }
        }
        __syncthreads();
        #pragma unroll
        for (int ks = 0; ks < 4; ++ks) {
            const int kb = ks * 64 + ((lane >> 4) << 4);
            bf16x8 afr[2][2], bfr[2][2];
            #pragma unroll
            for (int rt = 0; rt < 2; ++rt) {
                const int row = wr * 32 + rt * 16 + (lane & 15);
                const int d = (row << 8) + (kb ^ ((row & 15) << 4));
                afr[rt][0] = *(const bf16x8*)(sA[0] + d);
                afr[rt][1] = *(const bf16x8*)(sA[1] + d);
            }
            #pragma unroll
            for (int ct = 0; ct < 2; ++ct) {
                const int row = wc * 32 + ct * 16 + (lane & 15);
                const int d = (row << 8) + (kb ^ ((row & 15) << 4));
                bfr[ct][0] = *(const bf16x8*)(sB[0] + d);
                bfr[ct][1] = *(const bf16x8*)(sB[1] + d);
            }
            #pragma unroll
            for (int rt = 0; rt < 2; ++rt)
                #pragma unroll
                for (int ct = 0; ct < 2; ++ct) {
                    acc[rt][ct] = __builtin_amdgcn_mfma_f32_16x16x32_bf16(afr[rt][0], bfr[ct][0], acc[rt][ct], 0, 0, 0);
                    acc[rt][ct] = __builtin_amdgcn_mfma_f32_16x16x32_bf16(afr[rt][0], bfr[ct][1], acc[rt][ct], 0, 0, 0);
                    acc[rt][ct] = __builtin_amdgcn_mfma_f32_16x16x32_bf16(afr[rt][1], bfr[ct][0], acc[rt][ct], 0, 0, 0);
                }
        }
    }

    #pragma unroll
    for (int rt = 0; rt < 2; ++rt)
        #pragma unroll
        for (int ct = 0; ct < 2; ++ct)
            #pragma unroll
            for (int r = 0; r < 4; ++r) {
                const int row = wr * 32 + rt * 16 + ((lane >> 4) << 2) + r;
                const int col = wc * 32 + ct * 16 + (lane & 15);
                const float v = acc[rt][ct][r];
                if (MODE == 0) {
                    const size_t o = (size_t)(nb * 64 + row) * 1024 + c0 + col;
                    const __bf16 h = (__bf16)v;
                    Oh[o] = h;
                    Ol[o] = (__bf16)(v - (float)h);
                } else {
                    SX[(size_t)(nb * 64 + row) * 256 + c0 + col] = v;
                }
            }
}

__global__ __launch_bounds__(1024) void split_S(const float* __restrict__ S,
    __bf16* __restrict__ Ah, __bf16* __restrict__ Al,
    __bf16* __restrict__ STh, __bf16* __restrict__ STl)
{
    __shared__ float tile[32][33];
    const int tx = threadIdx.x & 31, ty = threadIdx.x >> 5;
    const int r0 = blockIdx.y * 32, c0 = blockIdx.x * 32;
    const float v = S[(size_t)(r0 + ty) * 1024 + c0 + tx];
    tile[ty][tx] = v;
    {
        const __bf16 h = (__bf16)v;
        const size_t o = (size_t)(r0 + ty) * 1024 + c0 + tx;
        Ah[o] = h; Al[o] = (__bf16)(v - (float)h);
    }
    __syncthreads();
    const float w = tile[tx][ty];
    const __bf16 h = (__bf16)w;
    const size_t o = (size_t)(c0 + ty) * 1024 + r0 + tx;
    STh[o] = h; STl[o] = (__bf16)(w - (float)h);
}

// row-major plane -> fragment layout
__global__ __launch_bounds__(256) void repack(const __bf16* __restrict__ src,
                                              __bf16* __restrict__ dst)
{
    const int g = blockIdx.x * 256 + threadIdx.x;      // one per 8 elems
    const int row = g >> 7;
    const int k0 = (g & 127) * 8;
    const bf16x8 v = *(const bf16x8*)(src + (size_t)row * 1024 + k0);
    const int rowblk = row >> 4;
    const int kblk = k0 >> 5;
    const int lanew = (row & 15) + (((k0 >> 3) & 3) << 4);
    *(bf16x8*)(dst + (((size_t)rowblk * 32 + kblk) * 64 + lanew) * 8) = v;
}

__global__ __launch_bounds__(256) void init_x0(const float* __restrict__ x0,
    float* __restrict__ SX, float* __restrict__ x_traj,
    __bf16* __restrict__ X0Th, __bf16* __restrict__ X0Tl)
{
    const int g = blockIdx.x * 256 + threadIdx.x;   // b*1024+n
    const int b = g >> 10, n = g & 1023;
    const f32x4 v = *(const f32x4*)(x0 + (size_t)g * 4);
    *(f32x4*)(SX + (size_t)n * 256 + b * 4) = v;
    *(f32x4*)(x_traj + (size_t)b * ((T_STEPS + 1) * 4096) + n * 4) = v;
    #pragma unroll
    for (int p = 0; p < 4; ++p) {
        const __bf16 h = (__bf16)v[p];
        const size_t o = (size_t)(b * 4 + p) * 1024 + n;
        X0Th[o] = h; X0Tl[o] = (__bf16)(v[p] - (float)h);
    }
}

// W_0 -> fragment layout planes
__global__ __launch_bounds__(256) void w0_kernel(const float* __restrict__ SX,
    const float* __restrict__ H1, const float* __restrict__ H2,
    __bf16* __restrict__ WFh, __bf16* __restrict__ WFl)
{
    __shared__ float h1s[512], h2s[128];
    const int tid = threadIdx.x;
    for (int i = tid; i < 512; i += 256) h1s[i] = H1[i];
    if (tid < 128) h2s[tid] = H2[tid];
    __syncthreads();
    const int g = blockIdx.x * 256 + tid;     // b*1024+n
    const int b = g >> 10, n = g & 1023;
    float sx[16];
    #pragma unroll
    for (int k = 0; k < 4; ++k) {
        const f32x4 v = *(const f32x4*)(SX + (size_t)(k * NN + n) * 256 + b * 4);
        #pragma unroll
        for (int p = 0; p < 4; ++p) sx[k * 4 + p] = v[p];
    }
    float w4[4] = {0.f, 0.f, 0.f, 0.f};
    #pragma unroll 4
    for (int f = 0; f < 32; ++f) {
        float z = 0.f;
        #pragma unroll
        for (int kp = 0; kp < 16; ++kp) z = fmaf(sx[kp], h1s[kp * 32 + f], z);
        z = tanhf(z);
        #pragma unroll
        for (int q = 0; q < 4; ++q) w4[q] = fmaf(z, h2s[f * 4 + q], w4[q]);
    }
    const int kblkw = n >> 5;
    const int lhi = ((n >> 3) & 3) << 4;
    const int jw = n & 7;
    #pragma unroll
    for (int q = 0; q < 4; ++q) {
        const int col = b * 4 + q;
        const int colblk = col >> 4;
        const int lanew = (col & 15) + lhi;
        const size_t o = (((size_t)colblk * 32 + kblkw) * 64 + lanew) * 8 + jw;
        const __bf16 h = (__bf16)w4[q];
        WFh[o] = h;
        WFl[o] = (__bf16)(w4[q] - (float)h);
    }
}

extern "C" void kernel_launch(void* const* d_in, const int* in_sizes, int n_in,
                              void* d_out, int out_size, void* d_ws, size_t ws_size,
                              hipStream_t stream)
{
    const float* x0 = (const float*)d_in[0];
    const float* S  = (const float*)d_in[1];
    const float* H1 = (const float*)d_in[2];
    const float* H2 = (const float*)d_in[3];

    float* x_traj = (float*)d_out;
    float* u_traj = x_traj + (size_t)BB * (T_STEPS + 1) * NN * 4;

    // workspace carve (total 38 MB)
    char* w = (char*)d_ws;
    __bf16* Ah_rm = (__bf16*)(w);                         // 8 MB  [0,8M)
    __bf16* Al_rm = (__bf16*)(w + (8u << 20));            // 8 MB
    __bf16* AhF   = (__bf16*)(w + (16u << 20));           // 8 MB
    __bf16* AlF   = (__bf16*)(w + (24u << 20));           // 8 MB
    float*  SX    = (float*) (w + (32u << 20));           // 4 MB
    __bf16* WF0h  = (__bf16*)(w + (36u << 20));           // 512 KB
    __bf16* WF0l  = (__bf16*)(w + (36u << 20) + (512u << 10));
    __bf16* WF1h  = (__bf16*)(w + (37u << 20));
    __bf16* WF1l  = (__bf16*)(w + (37u << 20) + (512u << 10));
    // setup-only aliases
    __bf16* STh   = AhF;                                  // dead before repack
    __bf16* STl   = AhF + (size_t)1024 * 1024;
    __bf16* X0Th  = WF1h;                                 // dead before step 0
    __bf16* X0Tl  = WF1l;

    dim3 blk(256);

    // 1) split S -> row-major planes (rows 0..1023 of Astack) + S^T planes
    split_S<<<dim3(32, 32), 1024, 0, stream>>>(S, Ah_rm, Al_rm, STh, STl);

    // 2) power chain: S^{j+1} = S^j @ S
    for (int j = 1; j <= 3; ++j) {
        gemm_core<0><<<dim3(16, 16), blk, 0, stream>>>(
            Ah_rm + (size_t)(j - 1) * 1024 * 1024, Al_rm + (size_t)(j - 1) * 1024 * 1024,
            STh, STl,
            Ah_rm + (size_t)j * 1024 * 1024, Al_rm + (size_t)j * 1024 * 1024, nullptr);
    }

    // 3) repack row-major planes -> fragment layout (after chain; frees ST alias)
    repack<<<dim3(2048), blk, 0, stream>>>(Ah_rm, AhF);
    repack<<<dim3(2048), blk, 0, stream>>>(Al_rm, AlF);

    // 4) SX_0 = x0 (transposed layout), x_traj[:,0], x0^T split planes
    init_x0<<<dim3(256), blk, 0, stream>>>(x0, SX, x_traj, X0Th, X0Tl);

    // 5) SX_{1..3} = [S;S^2;S^3] @ x0   (row-major A still intact)
    gemm_core<1><<<dim3(4, 48), blk, 0, stream>>>(
        Ah_rm, Al_rm, X0Th, X0Tl, nullptr, nullptr, SX + (size_t)1024 * 256);

    // 6) W_0 -> fragment planes
    w0_kernel<<<dim3(256), blk, 0, stream>>>(SX, H1, H2, WF0h, WF0l);

    // 7) rollout: one fused pipelined kernel per step, W double-buffered
    for (int t = 0; t < T_STEPS; ++t) {
        const __bf16* bh = (t & 1) ? WF1h : WF0h;
        const __bf16* bl = (t & 1) ? WF1l : WF0l;
        __bf16* oh = (t & 1) ? WF0h : WF1h;
        __bf16* ol = (t & 1) ? WF0l : WF1l;
        step_kernel<<<dim3(256), blk, 0, stream>>>(
            AhF, AlF, bh, bl, SX, x_traj, u_traj, H1, H2, oh, ol, t);
    }
}